// Round 2
// baseline (876.401 us; speedup 1.0000x reference)
//
#include <hip/hip_runtime.h>
#include <stdint.h>

typedef short short8 __attribute__((ext_vector_type(8)));
typedef float floatx4 __attribute__((ext_vector_type(4)));

constexpr int cFH = 11, cFW = 20, cP = 2784, cPM1 = 2783, cD = 704;
constexpr int cAFC = 64, cBBC = 512, cNB = 8, cNPAD = 2816, cM = 22272;

static __device__ __forceinline__ float bf2f(unsigned short u) {
  union { unsigned u32; float f; } v; v.u32 = ((unsigned)u) << 16; return v.f;
}
static __device__ __forceinline__ unsigned short f2bf(float f) {
  union { float f; unsigned u; } v; v.f = f;
  unsigned r = v.u + 0x7fffu + ((v.u >> 16) & 1u);
  return (unsigned short)(r >> 16);
}

// ---------------- 1x1 conv: f[b][o][y][x] = sum_c x[b][c][y][x]*w[o][c] + bias[o]
__global__ void k_conv(const float* __restrict__ x, const float* __restrict__ w,
                       const float* __restrict__ bias, float* __restrict__ f) {
  int idx = blockIdx.x * 256 + threadIdx.x;
  if (idx >= cNB * cAFC * cFH * cFW) return;
  int yx = idx % (cFH * cFW);
  int o  = (idx / (cFH * cFW)) % cAFC;
  int b  = idx / (cFH * cFW * cAFC);
  const float* xp = x + (size_t)b * cBBC * cFH * cFW + yx;
  const float* wp = w + (size_t)o * cBBC;
  float acc = 0.f;
#pragma unroll 8
  for (int c = 0; c < cBBC; ++c) acc += xp[(size_t)c * (cFH * cFW)] * wp[c];
  f[idx] = acc + bias[o];
}

// ---------------- gather -> feat bf16 [22272][704], d = o*11 + i
__global__ void k_gather(const float* __restrict__ f, const int* __restrict__ cut_x,
                         const unsigned char* __restrict__ invalid,
                         unsigned short* __restrict__ feat) {
  int idx = blockIdx.x * 256 + threadIdx.x;
  if (idx >= cM * cD) return;
  int d   = idx % cD;
  int row = idx / cD;           // b*2784 + p
  int p = row % cP;
  int b = row / cP;
  int o = d / cFH, i = d % cFH;
  int cx = cut_x[p * cFH + i];
  float v = invalid[p * cFH + i] ? 0.f : f[(((b * cAFC) + o) * cFH + i) * cFW + cx];
  feat[idx] = f2bf(v);
}

// ---------------- feat -> featT bf16 (per-batch [704][2784])
__global__ void k_transpose(const unsigned short* __restrict__ feat,
                            unsigned short* __restrict__ featT, int b_base) {
  __shared__ unsigned short tile[64][66];
  int bz = blockIdx.z;
  int b  = b_base + bz;
  int p0 = blockIdx.x * 64, d0 = blockIdx.y * 64;
  int t = threadIdx.x;
#pragma unroll
  for (int m = 0; m < 16; ++m) {
    int idx = t + m * 256; int r = idx >> 6, c = idx & 63;
    int p = p0 + r;
    tile[r][c] = (p < cP) ? feat[((size_t)b * cP + p) * cD + d0 + c] : (unsigned short)0;
  }
  __syncthreads();
#pragma unroll
  for (int m = 0; m < 16; ++m) {
    int idx = t + m * 256; int r = idx >> 6, c = idx & 63;
    int p = p0 + c;
    if (p < cP) featT[((size_t)bz * cD + d0 + r) * cP + p] = tile[c][r];
  }
}

// ---------------- att_w fp32 -> bf16, padded to 2816 rows (zeros)
__global__ void k_cvt_attw(const float* __restrict__ att_w, unsigned short* __restrict__ attw) {
  int idx = blockIdx.x * 256 + threadIdx.x;
  if (idx >= cNPAD * cD) return;
  int r = idx / cD;
  attw[idx] = (r < cPM1) ? f2bf(att_w[idx]) : (unsigned short)0;
}

// ---------------- Wt bf16 [80][1408]: rows 0..72 reg_w, 73..74 cls_w, rest 0
__global__ void k_build_wt(const float* __restrict__ reg_w, const float* __restrict__ cls_w,
                           unsigned short* __restrict__ Wt) {
  int idx = blockIdx.x * 256 + threadIdx.x;
  if (idx >= 80 * 1408) return;
  int r = idx / 1408, k = idx % 1408;
  float v = 0.f;
  if (r < 73) v = reg_w[(size_t)r * 1408 + k];
  else if (r < 75) v = cls_w[(size_t)(r - 73) * 1408 + k];
  Wt[idx] = f2bf(v);
}

// ---------------- zero diagonal of Pp
__global__ void k_diag(unsigned short* __restrict__ Pp, int nrows) {
  int i = blockIdx.x * 256 + threadIdx.x;
  if (i < nrows) Pp[(size_t)i * cP + (i % cP)] = 0;
}

// ---------------- GEMM 1: S = feat @ attw^T, +att_b, exp, scatter-store to Pp (diag skip)
__global__ __launch_bounds__(256, 2) void k_gemm_s(
    const unsigned short* __restrict__ feat, const unsigned short* __restrict__ attw,
    const float* __restrict__ att_b, unsigned short* __restrict__ Pp,
    int m_base, int m_count, int pp_base) {
  int tid = threadIdx.x;
  int w = tid >> 6, l = tid & 63, lr = l & 15, lg = l >> 4;
  int m0 = m_base + blockIdx.x * 128;
  int n0 = blockIdx.y * 128;
  floatx4 zero = {0.f, 0.f, 0.f, 0.f};
  floatx4 acc[2][8];
#pragma unroll
  for (int a = 0; a < 2; ++a)
#pragma unroll
    for (int q = 0; q < 8; ++q) acc[a][q] = zero;
  int lastRow = m_base + m_count - 1;
  const unsigned short* pa[2];
#pragma unroll
  for (int mt = 0; mt < 2; ++mt) {
    int r = m0 + w * 32 + mt * 16 + lr;
    r = r < lastRow ? r : lastRow;
    pa[mt] = feat + (size_t)r * cD;
  }
  const unsigned short* pb[8];
#pragma unroll
  for (int nt = 0; nt < 8; ++nt) pb[nt] = attw + (size_t)(n0 + nt * 16 + lr) * cD;
  int dof = lg * 8;
  for (int kk = 0; kk < 22; ++kk) {
    int d = kk * 32 + dof;
    short8 av[2], bv[8];
#pragma unroll
    for (int mt = 0; mt < 2; ++mt) av[mt] = *(const short8*)(pa[mt] + d);
#pragma unroll
    for (int nt = 0; nt < 8; ++nt) bv[nt] = *(const short8*)(pb[nt] + d);
#pragma unroll
    for (int mt = 0; mt < 2; ++mt)
#pragma unroll
      for (int nt = 0; nt < 8; ++nt)
        acc[mt][nt] = __builtin_amdgcn_mfma_f32_16x16x32_bf16(av[mt], bv[nt], acc[mt][nt], 0, 0, 0);
  }
#pragma unroll
  for (int nt = 0; nt < 8; ++nt) {
    int k = n0 + nt * 16 + lr;
    if (k >= cPM1) continue;
    float ab = att_b[k];
#pragma unroll
    for (int mt = 0; mt < 2; ++mt) {
#pragma unroll
      for (int r = 0; r < 4; ++r) {
        int i = m0 + w * 32 + mt * 16 + lg * 4 + r;
        if (i - m_base >= m_count) continue;
        float e = __expf(acc[mt][nt][r] + ab);
        int pl = i % cP;
        int j = k + (k >= pl ? 1 : 0);
        Pp[(size_t)(i - pp_base) * cP + j] = f2bf(e);
      }
    }
  }
}

// ---------------- GEMM 2: att_feat = (Pp @ featT^T) / rowsum(Pp)
__global__ __launch_bounds__(256, 2) void k_gemm_pv(
    const unsigned short* __restrict__ Pp, const unsigned short* __restrict__ featT,
    unsigned short* __restrict__ af,
    int b_base, int pp_base, int ft_base, int af_base) {
  __shared__ float ls[128];
  int tid = threadIdx.x;
  int w = tid >> 6, l = tid & 63, lr = l & 15, lg = l >> 4;
  int mtile = blockIdx.x;
  int b = b_base + mtile / 22;
  int m0l = (mtile % 22) * 128;
  int rlen = cP - m0l; rlen = rlen < 128 ? rlen : 128;
  int n0 = blockIdx.y * 128;
  floatx4 zero = {0.f, 0.f, 0.f, 0.f};
  floatx4 acc[2][8];
#pragma unroll
  for (int a = 0; a < 2; ++a)
#pragma unroll
    for (int q = 0; q < 8; ++q) acc[a][q] = zero;
  float lsum[2] = {0.f, 0.f};
  const unsigned short* pa[2];
#pragma unroll
  for (int mt = 0; mt < 2; ++mt) {
    int rl = m0l + w * 32 + mt * 16 + lr;
    rl = rl < (cP - 1) ? rl : (cP - 1);
    pa[mt] = Pp + (size_t)(b * cP + rl - pp_base) * cP;
  }
  const unsigned short* pb[8];
#pragma unroll
  for (int nt = 0; nt < 8; ++nt) {
    int dd = n0 + nt * 16 + lr;
    dd = dd < (cD - 1) ? dd : (cD - 1);
    pb[nt] = featT + ((size_t)(b - ft_base) * cD + dd) * cP;
  }
  int jof = lg * 8;
  for (int j0 = 0; j0 < cP; j0 += 32) {
    int jj = j0 + jof;
    short8 av[2], bv[8];
#pragma unroll
    for (int mt = 0; mt < 2; ++mt) av[mt] = *(const short8*)(pa[mt] + jj);
#pragma unroll
    for (int nt = 0; nt < 8; ++nt) bv[nt] = *(const short8*)(pb[nt] + jj);
#pragma unroll
    for (int mt = 0; mt < 2; ++mt)
#pragma unroll
      for (int e = 0; e < 8; ++e) lsum[mt] += bf2f((unsigned short)av[mt][e]);
#pragma unroll
    for (int mt = 0; mt < 2; ++mt)
#pragma unroll
      for (int nt = 0; nt < 8; ++nt)
        acc[mt][nt] = __builtin_amdgcn_mfma_f32_16x16x32_bf16(av[mt], bv[nt], acc[mt][nt], 0, 0, 0);
  }
#pragma unroll
  for (int mt = 0; mt < 2; ++mt) {
    lsum[mt] += __shfl_xor(lsum[mt], 16);
    lsum[mt] += __shfl_xor(lsum[mt], 32);
  }
  if (lg == 0) { ls[w * 32 + lr] = lsum[0]; ls[w * 32 + 16 + lr] = lsum[1]; }
  __syncthreads();
#pragma unroll
  for (int mt = 0; mt < 2; ++mt)
#pragma unroll
    for (int nt = 0; nt < 8; ++nt)
#pragma unroll
      for (int r = 0; r < 4; ++r) {
        int rloc = w * 32 + mt * 16 + lg * 4 + r;
        int dd = n0 + nt * 16 + lr;
        if (rloc < rlen && dd < cD) {
          float v = acc[mt][nt][r] / ls[rloc];
          af[((size_t)(b * cP + m0l + rloc) - af_base) * cD + dd] = f2bf(v);
        }
      }
}

// ---------------- GEMM 3: [att_feat|feat] @ Wt^T + epilogue (anchors, outputs)
__global__ __launch_bounds__(256, 2) void k_gemm_out(
    const unsigned short* __restrict__ af, const unsigned short* __restrict__ feat,
    const unsigned short* __restrict__ Wt,
    const float* __restrict__ reg_b, const float* __restrict__ cls_b,
    const float* __restrict__ anchors,
    float* __restrict__ out0, float* __restrict__ out1,
    float* __restrict__ out2, float* __restrict__ out3,
    int m_base, int m_count, int af_base) {
  int tid = threadIdx.x;
  int w = tid >> 6, l = tid & 63, lr = l & 15, lg = l >> 4;
  int m0 = m_base + blockIdx.x * 128;
  floatx4 zero = {0.f, 0.f, 0.f, 0.f};
  floatx4 acc[2][5];
#pragma unroll
  for (int a = 0; a < 2; ++a)
#pragma unroll
    for (int q = 0; q < 5; ++q) acc[a][q] = zero;
  int lastRow = m_base + m_count - 1;
  int rA[2];
#pragma unroll
  for (int mt = 0; mt < 2; ++mt) {
    int r = m0 + w * 32 + mt * 16 + lr;
    rA[mt] = r < lastRow ? r : lastRow;
  }
  const unsigned short* pb[5];
#pragma unroll
  for (int nt = 0; nt < 5; ++nt) pb[nt] = Wt + (size_t)(nt * 16 + lr) * 1408;
  int kof = lg * 8;
  for (int kk = 0; kk < 44; ++kk) {
    int kb = kk * 32 + kof;
    short8 av[2], bv[5];
#pragma unroll
    for (int mt = 0; mt < 2; ++mt) {
      if (kk < 22) av[mt] = *(const short8*)(af + ((size_t)rA[mt] - af_base) * cD + kb);
      else         av[mt] = *(const short8*)(feat + (size_t)rA[mt] * cD + (kb - 704));
    }
#pragma unroll
    for (int nt = 0; nt < 5; ++nt) bv[nt] = *(const short8*)(pb[nt] + kb);
#pragma unroll
    for (int mt = 0; mt < 2; ++mt)
#pragma unroll
      for (int nt = 0; nt < 5; ++nt)
        acc[mt][nt] = __builtin_amdgcn_mfma_f32_16x16x32_bf16(av[mt], bv[nt], acc[mt][nt], 0, 0, 0);
  }
#pragma unroll
  for (int mt = 0; mt < 2; ++mt)
#pragma unroll
    for (int nt = 0; nt < 5; ++nt)
#pragma unroll
      for (int r = 0; r < 4; ++r) {
        int i = m0 + w * 32 + mt * 16 + lg * 4 + r;
        if (i - m_base >= m_count) continue;
        int o = nt * 16 + lr;
        int p = i % cP;
        float v = acc[mt][nt][r];
        const float* an = anchors + (size_t)p * 74;
        if (o == 0)        { out2[i] = an[1] + v + reg_b[0]; out1[i] = an[0]; }
        else if (o < 73)   { out0[(size_t)i * 72 + (o - 1)] = an[1 + o] + v + reg_b[o]; }
        else if (o == 73)  { out3[(size_t)i * 2]     = v + cls_b[0]; }
        else if (o == 74)  { out3[(size_t)i * 2 + 1] = v + cls_b[1]; }
      }
}

extern "C" void kernel_launch(void* const* d_in, const int* in_sizes, int n_in,
                              void* d_out, int out_size, void* d_ws, size_t ws_size,
                              hipStream_t stream) {
  const float* x       = (const float*)d_in[0];
  const float* conv_w  = (const float*)d_in[1];
  const float* conv_b  = (const float*)d_in[2];
  const float* att_w   = (const float*)d_in[3];
  const float* att_b   = (const float*)d_in[4];
  const float* cls_w   = (const float*)d_in[5];
  const float* cls_b   = (const float*)d_in[6];
  const float* reg_w   = (const float*)d_in[7];
  const float* reg_b   = (const float*)d_in[8];
  const float* anchors = (const float*)d_in[9];
  const int*   cut_x   = (const int*)d_in[10];
  const unsigned char* invalid = (const unsigned char*)d_in[11];
  float* out0 = (float*)d_out;
  float* out1 = out0 + (size_t)cM * 72;
  float* out2 = out1 + cM;
  float* out3 = out2 + cM;

  size_t off = 0;
  char* base = (char*)d_ws;
  auto carve = [&](size_t bytes) -> void* {
    void* r = base + off; off += (bytes + 255) & ~(size_t)255; return r;
  };
  float* fbuf          = (float*)carve((size_t)cNB * cAFC * cFH * cFW * 4);
  unsigned short* feat = (unsigned short*)carve((size_t)cM * cD * 2);
  unsigned short* attw = (unsigned short*)carve((size_t)cNPAD * cD * 2);
  unsigned short* Wt   = (unsigned short*)carve((size_t)80 * 1408 * 2);

  size_t featT_full = (size_t)cNB * cD * cP * 2, featT_one = (size_t)cD * cP * 2;
  size_t af_full    = (size_t)cM * cD * 2,       af_one    = (size_t)cP * cD * 2;
  size_t pp_full    = (size_t)cM * cP * 2,       pp_one    = (size_t)cP * cP * 2;

  size_t needA = off + featT_full + af_full + pp_full;
  size_t needB = off + featT_full + af_full + pp_one;
  int mode = (ws_size >= needA) ? 0 : ((ws_size >= needB) ? 1 : 2);

  unsigned short *featT, *af, *Pp;
  if (mode == 0)      { featT = (unsigned short*)carve(featT_full); af = (unsigned short*)carve(af_full); Pp = (unsigned short*)carve(pp_full); }
  else if (mode == 1) { featT = (unsigned short*)carve(featT_full); af = (unsigned short*)carve(af_full); Pp = (unsigned short*)carve(pp_one); }
  else                { featT = (unsigned short*)carve(featT_one);  af = (unsigned short*)carve(af_one);  Pp = (unsigned short*)carve(pp_one); }

  k_conv<<<440, 256, 0, stream>>>(x, conv_w, conv_b, fbuf);
  k_gather<<<(cM * cD + 255) / 256, 256, 0, stream>>>(fbuf, cut_x, invalid, feat);
  k_cvt_attw<<<(cNPAD * cD + 255) / 256, 256, 0, stream>>>(att_w, attw);
  k_build_wt<<<(80 * 1408 + 255) / 256, 256, 0, stream>>>(reg_w, cls_w, Wt);

  if (mode == 0) {
    k_transpose<<<dim3(44, 11, 8), 256, 0, stream>>>(feat, featT, 0);
    k_gemm_s<<<dim3(174, 22), 256, 0, stream>>>(feat, attw, att_b, Pp, 0, cM, 0);
    k_diag<<<(cM + 255) / 256, 256, 0, stream>>>(Pp, cM);
    k_gemm_pv<<<dim3(176, 6), 256, 0, stream>>>(Pp, featT, af, 0, 0, 0, 0);
    k_gemm_out<<<174, 256, 0, stream>>>(af, feat, Wt, reg_b, cls_b, anchors,
                                        out0, out1, out2, out3, 0, cM, 0);
  } else if (mode == 1) {
    k_transpose<<<dim3(44, 11, 8), 256, 0, stream>>>(feat, featT, 0);
    for (int b = 0; b < cNB; ++b) {
      k_gemm_s<<<dim3(22, 22), 256, 0, stream>>>(feat, attw, att_b, Pp, b * cP, cP, b * cP);
      k_diag<<<(cP + 255) / 256, 256, 0, stream>>>(Pp, cP);
      k_gemm_pv<<<dim3(22, 6), 256, 0, stream>>>(Pp, featT, af, b, b * cP, 0, 0);
    }
    k_gemm_out<<<174, 256, 0, stream>>>(af, feat, Wt, reg_b, cls_b, anchors,
                                        out0, out1, out2, out3, 0, cM, 0);
  } else {
    for (int b = 0; b < cNB; ++b) {
      k_transpose<<<dim3(44, 11, 1), 256, 0, stream>>>(feat, featT, b);
      k_gemm_s<<<dim3(22, 22), 256, 0, stream>>>(feat, attw, att_b, Pp, b * cP, cP, b * cP);
      k_diag<<<(cP + 255) / 256, 256, 0, stream>>>(Pp, cP);
      k_gemm_pv<<<dim3(22, 6), 256, 0, stream>>>(Pp, featT, af, b, b * cP, b, b * cP);
      k_gemm_out<<<22, 256, 0, stream>>>(af, feat, Wt, reg_b, cls_b, anchors,
                                         out0, out1, out2, out3, b * cP, cP, b * cP);
    }
  }
}

// Round 3
// 502.810 us; speedup vs baseline: 1.7430x; 1.7430x over previous
//
#include <hip/hip_runtime.h>
#include <stdint.h>

typedef short short8 __attribute__((ext_vector_type(8)));
typedef float floatx4 __attribute__((ext_vector_type(4)));
typedef unsigned short ushort_t;

constexpr int cFH = 11, cFW = 20, cP = 2784, cPM1 = 2783, cD = 704;
constexpr int cAFC = 64, cBBC = 512, cNB = 8, cNPAD = 2816, cM = 22272;
constexpr int cFTR = 768;   // featT padded rows

static __device__ __forceinline__ float bf2f(unsigned short u) {
  union { unsigned u32; float f; } v; v.u32 = ((unsigned)u) << 16; return v.f;
}
static __device__ __forceinline__ unsigned short f2bf(float f) {
  union { float f; unsigned u; } v; v.f = f;
  unsigned r = v.u + 0x7fffu + ((v.u >> 16) & 1u);
  return (unsigned short)(r >> 16);
}
static __device__ __forceinline__ int imin(int a, int b) { return a < b ? a : b; }

// async global->LDS, 16B per lane, wave-uniform LDS base + lane*16
static __device__ __forceinline__ void gload16(const ushort_t* g, ushort_t* l) {
  __builtin_amdgcn_global_load_lds(
      (const __attribute__((address_space(1))) unsigned int*)g,
      (__attribute__((address_space(3))) unsigned int*)l, 16, 0, 0);
}

// ---------------- 1x1 conv
__global__ void k_conv(const float* __restrict__ x, const float* __restrict__ w,
                       const float* __restrict__ bias, float* __restrict__ f) {
  int idx = blockIdx.x * 256 + threadIdx.x;
  if (idx >= cNB * cAFC * cFH * cFW) return;
  int yx = idx % (cFH * cFW);
  int o  = (idx / (cFH * cFW)) % cAFC;
  int b  = idx / (cFH * cFW * cAFC);
  const float* xp = x + (size_t)b * cBBC * cFH * cFW + yx;
  const float* wp = w + (size_t)o * cBBC;
  float acc = 0.f;
#pragma unroll 8
  for (int c = 0; c < cBBC; ++c) acc += xp[(size_t)c * (cFH * cFW)] * wp[c];
  f[idx] = acc + bias[o];
}

// ---------------- gather -> feat bf16 [22272][704]
__global__ void k_gather(const float* __restrict__ f, const int* __restrict__ cut_x,
                         const unsigned char* __restrict__ invalid,
                         ushort_t* __restrict__ feat) {
  int idx = blockIdx.x * 256 + threadIdx.x;
  if (idx >= cM * cD) return;
  int d   = idx % cD;
  int row = idx / cD;
  int p = row % cP;
  int b = row / cP;
  int o = d / cFH, i = d % cFH;
  int cx = cut_x[p * cFH + i];
  float v = invalid[p * cFH + i] ? 0.f : f[(((b * cAFC) + o) * cFH + i) * cFW + cx];
  feat[idx] = f2bf(v);
}

// ---------------- feat -> featT bf16 [bz][768][2816] (cols >= cP zeroed, rows >= cD untouched)
__global__ void k_transpose(const ushort_t* __restrict__ feat,
                            ushort_t* __restrict__ featT, int b_base) {
  __shared__ ushort_t tile[64][66];
  int bz = blockIdx.z;
  int b  = b_base + bz;
  int p0 = blockIdx.x * 64, d0 = blockIdx.y * 64;
  int t = threadIdx.x;
#pragma unroll
  for (int m = 0; m < 16; ++m) {
    int idx = t + m * 256; int r = idx >> 6, c = idx & 63;
    int p = p0 + r;
    tile[r][c] = (p < cP) ? feat[((size_t)b * cP + p) * cD + d0 + c] : (ushort_t)0;
  }
  __syncthreads();
#pragma unroll
  for (int m = 0; m < 16; ++m) {
    int idx = t + m * 256; int r = idx >> 6, c = idx & 63;
    featT[((size_t)bz * cFTR + d0 + r) * cNPAD + p0 + c] = tile[c][r];
  }
}

// ---------------- att_w fp32 -> bf16, padded to 2816 rows
__global__ void k_cvt_attw(const float* __restrict__ att_w, ushort_t* __restrict__ attw) {
  int idx = blockIdx.x * 256 + threadIdx.x;
  if (idx >= cNPAD * cD) return;
  int r = idx / cD;
  attw[idx] = (r < cPM1) ? f2bf(att_w[idx]) : (ushort_t)0;
}

// ---------------- Wt bf16 [80][1408]
__global__ void k_build_wt(const float* __restrict__ reg_w, const float* __restrict__ cls_w,
                           ushort_t* __restrict__ Wt) {
  int idx = blockIdx.x * 256 + threadIdx.x;
  if (idx >= 80 * 1408) return;
  int r = idx / 1408, k = idx % 1408;
  float v = 0.f;
  if (r < 73) v = reg_w[(size_t)r * 1408 + k];
  else if (r < 75) v = cls_w[(size_t)(r - 73) * 1408 + k];
  Wt[idx] = f2bf(v);
}

// ---------------- zero diagonal of Pp
__global__ void k_diag(ushort_t* __restrict__ Pp, int nrows, int p_base) {
  int i = blockIdx.x * 256 + threadIdx.x;
  if (i < nrows) Pp[(size_t)i * cNPAD + ((p_base + i) % cP)] = 0;
}

// ---------------- denom[i] = sum over 44 partial slots
__global__ void k_denom(const float* __restrict__ partial, float* __restrict__ denom, int n) {
  int i = blockIdx.x * 256 + threadIdx.x;
  if (i >= n) return;
  float s = 0.f;
#pragma unroll 4
  for (int q = 0; q < 44; ++q) s += partial[(size_t)q * cM + i];
  denom[i] = s;
}

// ---------------- GEMM 1 (staged): S = feat @ attw^T; exp; scatter into Pp; row-partials
__global__ __launch_bounds__(256, 3) void k_gemm_s2(
    const ushort_t* __restrict__ feat, const ushort_t* __restrict__ attw,
    const float* __restrict__ att_b, ushort_t* __restrict__ Pp,
    float* __restrict__ partial, int m_base, int m_count, int pp_base) {
  __shared__ __align__(16) ushort_t sA[2][128 * 32];
  __shared__ __align__(16) ushort_t sB[2][128 * 32];
  int tid = threadIdx.x;
  int w = tid >> 6, l = tid & 63, lr = l & 15, lg = l >> 4;
  int wr = (w >> 1) * 64, wc = (w & 1) * 64;
  int m0 = m_base + blockIdx.x * 128;
  int n0 = blockIdx.y * 128;
  int rmaxA = m_base + m_count - 1;

  // staging coords: thread t handles row q*64 + w*16 + (l>>2), col (l&3)*8
  int srow = w * 16 + (l >> 2), scol = (l & 3) * 8;
  const ushort_t* a0 = feat + (size_t)imin(m0 + srow, rmaxA) * cD + scol;
  const ushort_t* a1 = feat + (size_t)imin(m0 + 64 + srow, rmaxA) * cD + scol;
  const ushort_t* b0 = attw + (size_t)(n0 + srow) * cD + scol;
  const ushort_t* b1 = attw + (size_t)(n0 + 64 + srow) * cD + scol;
  int lbase = w * 512;  // per-wave LDS base (ushort elems)

  floatx4 acc[4][4];
  floatx4 zero = {0.f, 0.f, 0.f, 0.f};
#pragma unroll
  for (int a = 0; a < 4; ++a)
#pragma unroll
    for (int q = 0; q < 4; ++q) acc[a][q] = zero;

  auto stage = [&](int buf) {
    gload16(a0, &sA[buf][lbase]);
    gload16(a1, &sA[buf][lbase + 2048]);
    gload16(b0, &sB[buf][lbase]);
    gload16(b1, &sB[buf][lbase + 2048]);
    a0 += 32; a1 += 32; b0 += 32; b1 += 32;
  };

  stage(0);
  __syncthreads();
  int cur = 0;
  constexpr int NK = cD / 32;  // 22
  for (int kk = 0; kk < NK; ++kk) {
    if (kk + 1 < NK) stage(cur ^ 1);
    short8 av[4], bv[4];
#pragma unroll
    for (int mt = 0; mt < 4; ++mt)
      av[mt] = *(const short8*)&sA[cur][(wr + mt * 16 + lr) * 32 + lg * 8];
#pragma unroll
    for (int nt = 0; nt < 4; ++nt)
      bv[nt] = *(const short8*)&sB[cur][(wc + nt * 16 + lr) * 32 + lg * 8];
#pragma unroll
    for (int mt = 0; mt < 4; ++mt)
#pragma unroll
      for (int nt = 0; nt < 4; ++nt)
        acc[mt][nt] = __builtin_amdgcn_mfma_f32_16x16x32_bf16(av[mt], bv[nt], acc[mt][nt], 0, 0, 0);
    __syncthreads();
    cur ^= 1;
  }

  // epilogue: exp, scatter store (diag skip), per-row partial sums
  int w1 = w & 1;
  float ab[4]; int kc[4];
#pragma unroll
  for (int nt = 0; nt < 4; ++nt) {
    int k = n0 + wc + nt * 16 + lr;
    kc[nt] = k;
    ab[nt] = (k < cPM1) ? att_b[k] : 0.f;
  }
#pragma unroll
  for (int mt = 0; mt < 4; ++mt) {
#pragma unroll
    for (int r = 0; r < 4; ++r) {
      int i = m0 + wr + mt * 16 + lg * 4 + r;
      int il = i - pp_base;
      bool rowok = (i - m_base) < m_count;
      int pl = i % cP;
      float s = 0.f;
#pragma unroll
      for (int nt = 0; nt < 4; ++nt) {
        int k = kc[nt];
        if (k < cPM1) {
          float e = __expf(acc[mt][nt][r] + ab[nt]);
          s += e;
          if (rowok) Pp[(size_t)il * cNPAD + k + (k >= pl ? 1 : 0)] = f2bf(e);
        } else if (k <= cNPAD - 2) {
          if (rowok) Pp[(size_t)il * cNPAD + k + 1] = 0;
        }
      }
      s += __shfl_xor(s, 1); s += __shfl_xor(s, 2);
      s += __shfl_xor(s, 4); s += __shfl_xor(s, 8);
      if (lr == 0 && rowok)
        partial[(size_t)(blockIdx.y * 2 + w1) * cM + il] = s;
    }
  }
}

// ---------------- GEMM 2 (staged): att_feat = (Pp @ featT^T) / denom
__global__ __launch_bounds__(256, 3) void k_gemm_pv2(
    const ushort_t* __restrict__ Pp, const ushort_t* __restrict__ featT,
    const float* __restrict__ denom, ushort_t* __restrict__ af,
    int b_base, int pp_base, int ft_base, int af_base) {
  __shared__ __align__(16) ushort_t sA[2][128 * 32];
  __shared__ __align__(16) ushort_t sB[2][128 * 32];
  int tid = threadIdx.x;
  int w = tid >> 6, l = tid & 63, lr = l & 15, lg = l >> 4;
  int wr = (w >> 1) * 64, wc = (w & 1) * 64;
  int mtile = blockIdx.x;
  int b = b_base + mtile / 22;
  int m0l = (mtile % 22) * 128;
  int n0 = blockIdx.y * 128;
  int bP = b * cP - pp_base;  // local base of this batch in Pp/denom

  int srow = w * 16 + (l >> 2), scol = (l & 3) * 8;
  const ushort_t* a0 = Pp + (size_t)(bP + imin(m0l + srow, cP - 1)) * cNPAD + scol;
  const ushort_t* a1 = Pp + (size_t)(bP + imin(m0l + 64 + srow, cP - 1)) * cNPAD + scol;
  const ushort_t* b0 = featT + ((size_t)(b - ft_base) * cFTR + n0 + srow) * cNPAD + scol;
  const ushort_t* b1 = featT + ((size_t)(b - ft_base) * cFTR + n0 + 64 + srow) * cNPAD + scol;
  int lbase = w * 512;

  floatx4 acc[4][4];
  floatx4 zero = {0.f, 0.f, 0.f, 0.f};
#pragma unroll
  for (int a = 0; a < 4; ++a)
#pragma unroll
    for (int q = 0; q < 4; ++q) acc[a][q] = zero;

  auto stage = [&](int buf) {
    gload16(a0, &sA[buf][lbase]);
    gload16(a1, &sA[buf][lbase + 2048]);
    gload16(b0, &sB[buf][lbase]);
    gload16(b1, &sB[buf][lbase + 2048]);
    a0 += 32; a1 += 32; b0 += 32; b1 += 32;
  };

  stage(0);
  __syncthreads();
  int cur = 0;
  constexpr int NK = cNPAD / 32;  // 88
  for (int kk = 0; kk < NK; ++kk) {
    if (kk + 1 < NK) stage(cur ^ 1);
    short8 av[4], bv[4];
#pragma unroll
    for (int mt = 0; mt < 4; ++mt)
      av[mt] = *(const short8*)&sA[cur][(wr + mt * 16 + lr) * 32 + lg * 8];
#pragma unroll
    for (int nt = 0; nt < 4; ++nt)
      bv[nt] = *(const short8*)&sB[cur][(wc + nt * 16 + lr) * 32 + lg * 8];
#pragma unroll
    for (int mt = 0; mt < 4; ++mt)
#pragma unroll
      for (int nt = 0; nt < 4; ++nt)
        acc[mt][nt] = __builtin_amdgcn_mfma_f32_16x16x32_bf16(av[mt], bv[nt], acc[mt][nt], 0, 0, 0);
    __syncthreads();
    cur ^= 1;
  }

#pragma unroll
  for (int mt = 0; mt < 4; ++mt)
#pragma unroll
    for (int nt = 0; nt < 4; ++nt)
#pragma unroll
      for (int r = 0; r < 4; ++r) {
        int p = m0l + wr + mt * 16 + lg * 4 + r;
        int dd = n0 + wc + nt * 16 + lr;
        if (p < cP && dd < cD) {
          float v = acc[mt][nt][r] / denom[bP + p];
          af[((size_t)(b * cP + p) - af_base) * cD + dd] = f2bf(v);
        }
      }
}

// ---------------- GEMM 3: [att_feat|feat] @ Wt^T + epilogue, M-tile 64
__global__ __launch_bounds__(256, 2) void k_gemm_out(
    const ushort_t* __restrict__ af, const ushort_t* __restrict__ feat,
    const ushort_t* __restrict__ Wt,
    const float* __restrict__ reg_b, const float* __restrict__ cls_b,
    const float* __restrict__ anchors,
    float* __restrict__ out0, float* __restrict__ out1,
    float* __restrict__ out2, float* __restrict__ out3,
    int m_base, int m_count, int af_base) {
  int tid = threadIdx.x;
  int w = tid >> 6, l = tid & 63, lr = l & 15, lg = l >> 4;
  int m0 = m_base + blockIdx.x * 64;
  floatx4 zero = {0.f, 0.f, 0.f, 0.f};
  floatx4 acc[5];
#pragma unroll
  for (int q = 0; q < 5; ++q) acc[q] = zero;
  int lastRow = m_base + m_count - 1;
  int rA = imin(m0 + w * 16 + lr, lastRow);
  const ushort_t* pAa = af + (size_t)(rA - af_base) * cD;
  const ushort_t* pAf = feat + (size_t)rA * cD;
  const ushort_t* pb[5];
#pragma unroll
  for (int nt = 0; nt < 5; ++nt) pb[nt] = Wt + (size_t)(nt * 16 + lr) * 1408;
  int kof = lg * 8;
  for (int kk = 0; kk < 22; ++kk) {
    int kb = kk * 32 + kof;
    short8 avv = *(const short8*)(pAa + kb);
#pragma unroll
    for (int nt = 0; nt < 5; ++nt) {
      short8 bvv = *(const short8*)(pb[nt] + kb);
      acc[nt] = __builtin_amdgcn_mfma_f32_16x16x32_bf16(avv, bvv, acc[nt], 0, 0, 0);
    }
  }
  for (int kk = 0; kk < 22; ++kk) {
    int kb = kk * 32 + kof;
    short8 avv = *(const short8*)(pAf + kb);
#pragma unroll
    for (int nt = 0; nt < 5; ++nt) {
      short8 bvv = *(const short8*)(pb[nt] + kb + 704);
      acc[nt] = __builtin_amdgcn_mfma_f32_16x16x32_bf16(avv, bvv, acc[nt], 0, 0, 0);
    }
  }
#pragma unroll
  for (int nt = 0; nt < 5; ++nt)
#pragma unroll
    for (int r = 0; r < 4; ++r) {
      int i = m0 + w * 16 + lg * 4 + r;
      if (i - m_base >= m_count) continue;
      int o = nt * 16 + lr;
      int p = i % cP;
      float v = acc[nt][r];
      const float* an = anchors + (size_t)p * 74;
      if (o == 0)        { out2[i] = an[1] + v + reg_b[0]; out1[i] = an[0]; }
      else if (o < 73)   { out0[(size_t)i * 72 + (o - 1)] = an[1 + o] + v + reg_b[o]; }
      else if (o == 73)  { out3[(size_t)i * 2]     = v + cls_b[0]; }
      else if (o == 74)  { out3[(size_t)i * 2 + 1] = v + cls_b[1]; }
    }
}

extern "C" void kernel_launch(void* const* d_in, const int* in_sizes, int n_in,
                              void* d_out, int out_size, void* d_ws, size_t ws_size,
                              hipStream_t stream) {
  const float* x       = (const float*)d_in[0];
  const float* conv_w  = (const float*)d_in[1];
  const float* conv_b  = (const float*)d_in[2];
  const float* att_w   = (const float*)d_in[3];
  const float* att_b   = (const float*)d_in[4];
  const float* cls_w   = (const float*)d_in[5];
  const float* cls_b   = (const float*)d_in[6];
  const float* reg_w   = (const float*)d_in[7];
  const float* reg_b   = (const float*)d_in[8];
  const float* anchors = (const float*)d_in[9];
  const int*   cut_x   = (const int*)d_in[10];
  const unsigned char* invalid = (const unsigned char*)d_in[11];
  float* out0 = (float*)d_out;
  float* out1 = out0 + (size_t)cM * 72;
  float* out2 = out1 + cM;
  float* out3 = out2 + cM;

  size_t off = 0;
  char* base = (char*)d_ws;
  auto carve = [&](size_t bytes) -> void* {
    void* r = base + off; off += (bytes + 255) & ~(size_t)255; return r;
  };
  float* fbuf            = (float*)carve((size_t)cNB * cAFC * cFH * cFW * 4);
  ushort_t* feat         = (ushort_t*)carve((size_t)cM * cD * 2);
  ushort_t* attw         = (ushort_t*)carve((size_t)cNPAD * cD * 2);
  ushort_t* Wt           = (ushort_t*)carve((size_t)80 * 1408 * 2);
  float* partial         = (float*)carve((size_t)44 * cM * 4);
  float* denom           = (float*)carve((size_t)cM * 4);

  size_t featT_full = (size_t)cNB * cFTR * cNPAD * 2, featT_one = (size_t)cFTR * cNPAD * 2;
  size_t af_full    = (size_t)cM * cD * 2,            af_one    = (size_t)cP * cD * 2;
  size_t pp_full    = (size_t)cM * cNPAD * 2,         pp_one    = (size_t)cNPAD * cNPAD * 2;

  size_t needA = off + featT_full + af_full + pp_full;
  size_t needB = off + featT_full + af_full + pp_one;
  int mode = (ws_size >= needA) ? 0 : ((ws_size >= needB) ? 1 : 2);

  ushort_t *featT, *af, *Pp;
  if (mode == 0)      { featT = (ushort_t*)carve(featT_full); af = (ushort_t*)carve(af_full); Pp = (ushort_t*)carve(pp_full); }
  else if (mode == 1) { featT = (ushort_t*)carve(featT_full); af = (ushort_t*)carve(af_full); Pp = (ushort_t*)carve(pp_one); }
  else                { featT = (ushort_t*)carve(featT_one);  af = (ushort_t*)carve(af_one);  Pp = (ushort_t*)carve(pp_one); }

  k_conv<<<440, 256, 0, stream>>>(x, conv_w, conv_b, fbuf);
  k_gather<<<(cM * cD + 255) / 256, 256, 0, stream>>>(fbuf, cut_x, invalid, feat);
  k_cvt_attw<<<(cNPAD * cD + 255) / 256, 256, 0, stream>>>(att_w, attw);
  k_build_wt<<<(80 * 1408 + 255) / 256, 256, 0, stream>>>(reg_w, cls_w, Wt);

  if (mode == 0) {
    k_transpose<<<dim3(44, 11, 8), 256, 0, stream>>>(feat, featT, 0);
    k_gemm_s2<<<dim3(174, 22), 256, 0, stream>>>(feat, attw, att_b, Pp, partial, 0, cM, 0);
    k_diag<<<(cM + 255) / 256, 256, 0, stream>>>(Pp, cM, 0);
    k_denom<<<(cM + 255) / 256, 256, 0, stream>>>(partial, denom, cM);
    k_gemm_pv2<<<dim3(176, 6), 256, 0, stream>>>(Pp, featT, denom, af, 0, 0, 0, 0);
    k_gemm_out<<<348, 256, 0, stream>>>(af, feat, Wt, reg_b, cls_b, anchors,
                                        out0, out1, out2, out3, 0, cM, 0);
  } else if (mode == 1) {
    k_transpose<<<dim3(44, 11, 8), 256, 0, stream>>>(feat, featT, 0);
    for (int b = 0; b < cNB; ++b) {
      k_gemm_s2<<<dim3(22, 22), 256, 0, stream>>>(feat, attw, att_b, Pp, partial, b * cP, cP, b * cP);
      k_diag<<<(cP + 255) / 256, 256, 0, stream>>>(Pp, cP, 0);
      k_denom<<<(cP + 255) / 256, 256, 0, stream>>>(partial, denom, cP);
      k_gemm_pv2<<<dim3(22, 6), 256, 0, stream>>>(Pp, featT, denom, af, b, b * cP, 0, 0);
    }
    k_gemm_out<<<348, 256, 0, stream>>>(af, feat, Wt, reg_b, cls_b, anchors,
                                        out0, out1, out2, out3, 0, cM, 0);
  } else {
    for (int b = 0; b < cNB; ++b) {
      k_transpose<<<dim3(44, 11, 1), 256, 0, stream>>>(feat, featT, b);
      k_gemm_s2<<<dim3(22, 22), 256, 0, stream>>>(feat, attw, att_b, Pp, partial, b * cP, cP, b * cP);
      k_diag<<<(cP + 255) / 256, 256, 0, stream>>>(Pp, cP, 0);
      k_denom<<<(cP + 255) / 256, 256, 0, stream>>>(partial, denom, cP);
      k_gemm_pv2<<<dim3(22, 6), 256, 0, stream>>>(Pp, featT, denom, af, b, b * cP, b, b * cP);
      k_gemm_out<<<44, 256, 0, stream>>>(af, feat, Wt, reg_b, cls_b, anchors,
                                         out0, out1, out2, out3, b * cP, cP, b * cP);
    }
  }
}

// Round 4
// 461.451 us; speedup vs baseline: 1.8992x; 1.0896x over previous
//
#include <hip/hip_runtime.h>
#include <stdint.h>

typedef short short8 __attribute__((ext_vector_type(8)));
typedef float floatx4 __attribute__((ext_vector_type(4)));
typedef unsigned short ushort_t;

constexpr int cFH = 11, cFW = 20, cP = 2784, cPM1 = 2783, cD = 704;
constexpr int cAFC = 64, cBBC = 512, cNB = 8, cNPAD = 2816, cM = 22272;
constexpr int cFTR = 768;   // featT padded rows

static __device__ __forceinline__ float bf2f(unsigned short u) {
  union { unsigned u32; float f; } v; v.u32 = ((unsigned)u) << 16; return v.f;
}
static __device__ __forceinline__ unsigned short f2bf(float f) {
  union { float f; unsigned u; } v; v.f = f;
  unsigned r = v.u + 0x7fffu + ((v.u >> 16) & 1u);
  return (unsigned short)(r >> 16);
}
static __device__ __forceinline__ int imin(int a, int b) { return a < b ? a : b; }

// bijective XCD-chunk swizzle (m204): consecutive logical blocks land on one XCD
static __device__ __forceinline__ int xcd_swz(int orig, int total) {
  int q = total >> 3, r = total & 7;
  int xcd = orig & 7, pos = orig >> 3;
  return (xcd < r ? xcd * (q + 1) : r * (q + 1) + (xcd - r) * q) + pos;
}

// async global->LDS, 16B per lane, wave-uniform LDS base + lane*16
static __device__ __forceinline__ void gload16(const ushort_t* g, ushort_t* l) {
  __builtin_amdgcn_global_load_lds(
      (const __attribute__((address_space(1))) unsigned int*)g,
      (__attribute__((address_space(3))) unsigned int*)l, 16, 0, 0);
}

// ---------------- 1x1 conv
__global__ void k_conv(const float* __restrict__ x, const float* __restrict__ w,
                       const float* __restrict__ bias, float* __restrict__ f) {
  int idx = blockIdx.x * 256 + threadIdx.x;
  if (idx >= cNB * cAFC * cFH * cFW) return;
  int yx = idx % (cFH * cFW);
  int o  = (idx / (cFH * cFW)) % cAFC;
  int b  = idx / (cFH * cFW * cAFC);
  const float* xp = x + (size_t)b * cBBC * cFH * cFW + yx;
  const float* wp = w + (size_t)o * cBBC;
  float acc = 0.f;
#pragma unroll 8
  for (int c = 0; c < cBBC; ++c) acc += xp[(size_t)c * (cFH * cFW)] * wp[c];
  f[idx] = acc + bias[o];
}

// ---------------- gather -> feat bf16 [22272][704]
__global__ void k_gather(const float* __restrict__ f, const int* __restrict__ cut_x,
                         const unsigned char* __restrict__ invalid,
                         ushort_t* __restrict__ feat) {
  int idx = blockIdx.x * 256 + threadIdx.x;
  if (idx >= cM * cD) return;
  int d   = idx % cD;
  int row = idx / cD;
  int p = row % cP;
  int b = row / cP;
  int o = d / cFH, i = d % cFH;
  int cx = cut_x[p * cFH + i];
  float v = invalid[p * cFH + i] ? 0.f : f[(((b * cAFC) + o) * cFH + i) * cFW + cx];
  feat[idx] = f2bf(v);
}

// ---------------- feat -> featT bf16 [bz][768][2816]
__global__ void k_transpose(const ushort_t* __restrict__ feat,
                            ushort_t* __restrict__ featT, int b_base) {
  __shared__ ushort_t tile[64][66];
  int bz = blockIdx.z;
  int b  = b_base + bz;
  int p0 = blockIdx.x * 64, d0 = blockIdx.y * 64;
  int t = threadIdx.x;
#pragma unroll
  for (int m = 0; m < 16; ++m) {
    int idx = t + m * 256; int r = idx >> 6, c = idx & 63;
    int p = p0 + r;
    tile[r][c] = (p < cP) ? feat[((size_t)b * cP + p) * cD + d0 + c] : (ushort_t)0;
  }
  __syncthreads();
#pragma unroll
  for (int m = 0; m < 16; ++m) {
    int idx = t + m * 256; int r = idx >> 6, c = idx & 63;
    featT[((size_t)bz * cFTR + d0 + r) * cNPAD + p0 + c] = tile[c][r];
  }
}

// ---------------- att_w fp32 -> bf16, padded to 2816 rows
__global__ void k_cvt_attw(const float* __restrict__ att_w, ushort_t* __restrict__ attw) {
  int idx = blockIdx.x * 256 + threadIdx.x;
  if (idx >= cNPAD * cD) return;
  int r = idx / cD;
  attw[idx] = (r < cPM1) ? f2bf(att_w[idx]) : (ushort_t)0;
}

// ---------------- Wt bf16 [80][1408]
__global__ void k_build_wt(const float* __restrict__ reg_w, const float* __restrict__ cls_w,
                           ushort_t* __restrict__ Wt) {
  int idx = blockIdx.x * 256 + threadIdx.x;
  if (idx >= 80 * 1408) return;
  int r = idx / 1408, k = idx % 1408;
  float v = 0.f;
  if (r < 73) v = reg_w[(size_t)r * 1408 + k];
  else if (r < 75) v = cls_w[(size_t)(r - 73) * 1408 + k];
  Wt[idx] = f2bf(v);
}

// ---------------- denom[i] = sum of 44 partial slots; also zero Pp diagonal
__global__ void k_denom(const float* __restrict__ partial, float* __restrict__ denom,
                        ushort_t* __restrict__ Pp, int n, int p_base) {
  int i = blockIdx.x * 256 + threadIdx.x;
  if (i >= n) return;
  float s = 0.f;
#pragma unroll 4
  for (int q = 0; q < 44; ++q) s += partial[(size_t)q * cM + i];
  denom[i] = s;
  Pp[(size_t)i * cNPAD + ((p_base + i) % cP)] = 0;
}

// ---------------- GEMM 1 (staged): S = feat @ attw^T; exp; scatter into Pp; row-partials
__global__ __launch_bounds__(256, 4) void k_gemm_s2(
    const ushort_t* __restrict__ feat, const ushort_t* __restrict__ attw,
    const float* __restrict__ att_b, ushort_t* __restrict__ Pp,
    float* __restrict__ partial, int m_base, int m_count, int pp_base) {
  __shared__ __align__(16) ushort_t sA[2][128 * 32];
  __shared__ __align__(16) ushort_t sB[2][128 * 32];
  int wg = xcd_swz(blockIdx.x, gridDim.x);
  int ntile = wg % 22, mtile = wg / 22;   // n fastest: A-panel shared by consecutive blocks
  int tid = threadIdx.x;
  int w = tid >> 6, l = tid & 63, lr = l & 15, lg = l >> 4;
  int wr = (w >> 1) * 64, wc = (w & 1) * 64;
  int m0 = m_base + mtile * 128;
  int n0 = ntile * 128;
  int rmaxA = m_base + m_count - 1;

  int srow = w * 16 + (l >> 2), scol = (l & 3) * 8;
  const ushort_t* a0 = feat + (size_t)imin(m0 + srow, rmaxA) * cD + scol;
  const ushort_t* a1 = feat + (size_t)imin(m0 + 64 + srow, rmaxA) * cD + scol;
  const ushort_t* b0 = attw + (size_t)(n0 + srow) * cD + scol;
  const ushort_t* b1 = attw + (size_t)(n0 + 64 + srow) * cD + scol;
  int lbase = w * 512;

  floatx4 acc[4][4];
  floatx4 zero = {0.f, 0.f, 0.f, 0.f};
#pragma unroll
  for (int a = 0; a < 4; ++a)
#pragma unroll
    for (int q = 0; q < 4; ++q) acc[a][q] = zero;

  auto stage = [&](int buf) {
    gload16(a0, &sA[buf][lbase]);
    gload16(a1, &sA[buf][lbase + 2048]);
    gload16(b0, &sB[buf][lbase]);
    gload16(b1, &sB[buf][lbase + 2048]);
    a0 += 32; a1 += 32; b0 += 32; b1 += 32;
  };

  stage(0);
  __syncthreads();
  int cur = 0;
  constexpr int NK = cD / 32;  // 22
  for (int kk = 0; kk < NK; ++kk) {
    if (kk + 1 < NK) stage(cur ^ 1);
    short8 av[4], bv[4];
#pragma unroll
    for (int mt = 0; mt < 4; ++mt)
      av[mt] = *(const short8*)&sA[cur][(wr + mt * 16 + lr) * 32 + lg * 8];
#pragma unroll
    for (int nt = 0; nt < 4; ++nt)
      bv[nt] = *(const short8*)&sB[cur][(wc + nt * 16 + lr) * 32 + lg * 8];
#pragma unroll
    for (int mt = 0; mt < 4; ++mt)
#pragma unroll
      for (int nt = 0; nt < 4; ++nt)
        acc[mt][nt] = __builtin_amdgcn_mfma_f32_16x16x32_bf16(av[mt], bv[nt], acc[mt][nt], 0, 0, 0);
    __syncthreads();
    cur ^= 1;
  }

  // epilogue: exp, scatter store (diag skip), per-row partial sums
  int w1 = w & 1;
  float ab[4]; int kc[4];
#pragma unroll
  for (int nt = 0; nt < 4; ++nt) {
    int k = n0 + wc + nt * 16 + lr;
    kc[nt] = k;
    ab[nt] = (k < cPM1) ? att_b[k] : 0.f;
  }
#pragma unroll
  for (int mt = 0; mt < 4; ++mt) {
#pragma unroll
    for (int r = 0; r < 4; ++r) {
      int i = m0 + wr + mt * 16 + lg * 4 + r;
      int il = i - pp_base;
      bool rowok = (i - m_base) < m_count;
      int pl = i % cP;
      float s = 0.f;
#pragma unroll
      for (int nt = 0; nt < 4; ++nt) {
        int k = kc[nt];
        if (k < cPM1) {
          float e = __expf(acc[mt][nt][r] + ab[nt]);
          s += e;
          if (rowok) Pp[(size_t)il * cNPAD + k + (k >= pl ? 1 : 0)] = f2bf(e);
        } else if (k <= cNPAD - 2) {
          if (rowok) Pp[(size_t)il * cNPAD + k + 1] = 0;
        }
      }
      s += __shfl_xor(s, 1); s += __shfl_xor(s, 2);
      s += __shfl_xor(s, 4); s += __shfl_xor(s, 8);
      if (lr == 0 && rowok)
        partial[(size_t)(ntile * 2 + w1) * cM + il] = s;
    }
  }
}

// ---------------- GEMM 2 (staged): att_feat = (Pp @ featT^T) / denom
// grid: nb_local * 22 * 6 linear; n fastest so 6 n-tiles sharing a Pp panel are adjacent
__global__ __launch_bounds__(256, 4) void k_gemm_pv2(
    const ushort_t* __restrict__ Pp, const ushort_t* __restrict__ featT,
    const float* __restrict__ denom, ushort_t* __restrict__ af,
    int b_base, int pp_base, int ft_base, int af_base) {
  __shared__ __align__(16) ushort_t sA[2][128 * 32];
  __shared__ __align__(16) ushort_t sB[2][128 * 32];
  int wg = xcd_swz(blockIdx.x, gridDim.x);
  int ntile = wg % 6;
  int t6 = wg / 6;
  int mtile = t6 % 22;
  int b = b_base + t6 / 22;
  int tid = threadIdx.x;
  int w = tid >> 6, l = tid & 63, lr = l & 15, lg = l >> 4;
  int wr = (w >> 1) * 64, wc = (w & 1) * 64;
  int m0l = mtile * 128;
  int n0 = ntile * 128;
  int bP = b * cP - pp_base;

  int srow = w * 16 + (l >> 2), scol = (l & 3) * 8;
  const ushort_t* a0 = Pp + (size_t)(bP + imin(m0l + srow, cP - 1)) * cNPAD + scol;
  const ushort_t* a1 = Pp + (size_t)(bP + imin(m0l + 64 + srow, cP - 1)) * cNPAD + scol;
  const ushort_t* b0 = featT + ((size_t)(b - ft_base) * cFTR + n0 + srow) * cNPAD + scol;
  const ushort_t* b1 = featT + ((size_t)(b - ft_base) * cFTR + n0 + 64 + srow) * cNPAD + scol;
  int lbase = w * 512;

  floatx4 acc[4][4];
  floatx4 zero = {0.f, 0.f, 0.f, 0.f};
#pragma unroll
  for (int a = 0; a < 4; ++a)
#pragma unroll
    for (int q = 0; q < 4; ++q) acc[a][q] = zero;

  auto stage = [&](int buf) {
    gload16(a0, &sA[buf][lbase]);
    gload16(a1, &sA[buf][lbase + 2048]);
    gload16(b0, &sB[buf][lbase]);
    gload16(b1, &sB[buf][lbase + 2048]);
    a0 += 32; a1 += 32; b0 += 32; b1 += 32;
  };

  stage(0);
  __syncthreads();
  int cur = 0;
  constexpr int NK = cP / 32;  // 87: pad columns 2784..2815 contribute zero, skipped
  for (int kk = 0; kk < NK; ++kk) {
    if (kk + 1 < NK) stage(cur ^ 1);
    short8 av[4], bv[4];
#pragma unroll
    for (int mt = 0; mt < 4; ++mt)
      av[mt] = *(const short8*)&sA[cur][(wr + mt * 16 + lr) * 32 + lg * 8];
#pragma unroll
    for (int nt = 0; nt < 4; ++nt)
      bv[nt] = *(const short8*)&sB[cur][(wc + nt * 16 + lr) * 32 + lg * 8];
#pragma unroll
    for (int mt = 0; mt < 4; ++mt)
#pragma unroll
      for (int nt = 0; nt < 4; ++nt)
        acc[mt][nt] = __builtin_amdgcn_mfma_f32_16x16x32_bf16(av[mt], bv[nt], acc[mt][nt], 0, 0, 0);
    __syncthreads();
    cur ^= 1;
  }

#pragma unroll
  for (int mt = 0; mt < 4; ++mt)
#pragma unroll
    for (int nt = 0; nt < 4; ++nt)
#pragma unroll
      for (int r = 0; r < 4; ++r) {
        int p = m0l + wr + mt * 16 + lg * 4 + r;
        int dd = n0 + wc + nt * 16 + lr;
        if (p < cP && dd < cD) {
          float v = acc[mt][nt][r] / denom[bP + p];
          af[((size_t)(b * cP + p) - af_base) * cD + dd] = f2bf(v);
        }
      }
}

// ---------------- GEMM 3 (staged A): [att_feat|feat] @ Wt^T + epilogue
__global__ __launch_bounds__(256, 4) void k_gemm_out(
    const ushort_t* __restrict__ af, const ushort_t* __restrict__ feat,
    const ushort_t* __restrict__ Wt,
    const float* __restrict__ reg_b, const float* __restrict__ cls_b,
    const float* __restrict__ anchors,
    float* __restrict__ out0, float* __restrict__ out1,
    float* __restrict__ out2, float* __restrict__ out3,
    int m_base, int m_count, int af_base) {
  __shared__ __align__(16) ushort_t sA[2][128 * 32];
  int tid = threadIdx.x;
  int w = tid >> 6, l = tid & 63, lr = l & 15, lg = l >> 4;
  int wr = w * 32;
  int m0 = m_base + blockIdx.x * 128;
  int lastRow = m_base + m_count - 1;

  int srow = w * 16 + (l >> 2), scol = (l & 3) * 8;
  const ushort_t* pa0_af = af + (size_t)(imin(m0 + srow, lastRow) - af_base) * cD + scol;
  const ushort_t* pa1_af = af + (size_t)(imin(m0 + 64 + srow, lastRow) - af_base) * cD + scol;
  const ushort_t* pa0_f  = feat + (size_t)imin(m0 + srow, lastRow) * cD + scol;
  const ushort_t* pa1_f  = feat + (size_t)imin(m0 + 64 + srow, lastRow) * cD + scol;
  int lbase = w * 512;

  floatx4 zero = {0.f, 0.f, 0.f, 0.f};
  floatx4 acc[2][5];
#pragma unroll
  for (int a = 0; a < 2; ++a)
#pragma unroll
    for (int q = 0; q < 5; ++q) acc[a][q] = zero;

  auto stageA = [&](int buf, int kk) {
    const ushort_t *s0, *s1;
    if (kk < 22) { s0 = pa0_af + kk * 32; s1 = pa1_af + kk * 32; }
    else         { s0 = pa0_f + (kk - 22) * 32; s1 = pa1_f + (kk - 22) * 32; }
    gload16(s0, &sA[buf][lbase]);
    gload16(s1, &sA[buf][lbase + 2048]);
  };

  stageA(0, 0);
  __syncthreads();
  int cur = 0;
  for (int kk = 0; kk < 44; ++kk) {
    if (kk + 1 < 44) stageA(cur ^ 1, kk + 1);
    int kb = kk * 32 + lg * 8;
    short8 avv[2];
#pragma unroll
    for (int mt = 0; mt < 2; ++mt)
      avv[mt] = *(const short8*)&sA[cur][(wr + mt * 16 + lr) * 32 + lg * 8];
#pragma unroll
    for (int nt = 0; nt < 5; ++nt) {
      short8 bvv = *(const short8*)(Wt + (size_t)(nt * 16 + lr) * 1408 + kb);
#pragma unroll
      for (int mt = 0; mt < 2; ++mt)
        acc[mt][nt] = __builtin_amdgcn_mfma_f32_16x16x32_bf16(avv[mt], bvv, acc[mt][nt], 0, 0, 0);
    }
    __syncthreads();
    cur ^= 1;
  }

#pragma unroll
  for (int mt = 0; mt < 2; ++mt)
#pragma unroll
    for (int nt = 0; nt < 5; ++nt)
#pragma unroll
      for (int r = 0; r < 4; ++r) {
        int i = m0 + wr + mt * 16 + lg * 4 + r;
        if (i - m_base >= m_count) continue;
        int o = nt * 16 + lr;
        int p = i % cP;
        float v = acc[mt][nt][r];
        const float* an = anchors + (size_t)p * 74;
        if (o == 0)        { out2[i] = an[1] + v + reg_b[0]; out1[i] = an[0]; }
        else if (o < 73)   { out0[(size_t)i * 72 + (o - 1)] = an[1 + o] + v + reg_b[o]; }
        else if (o == 73)  { out3[(size_t)i * 2]     = v + cls_b[0]; }
        else if (o == 74)  { out3[(size_t)i * 2 + 1] = v + cls_b[1]; }
      }
}

extern "C" void kernel_launch(void* const* d_in, const int* in_sizes, int n_in,
                              void* d_out, int out_size, void* d_ws, size_t ws_size,
                              hipStream_t stream) {
  const float* x       = (const float*)d_in[0];
  const float* conv_w  = (const float*)d_in[1];
  const float* conv_b  = (const float*)d_in[2];
  const float* att_w   = (const float*)d_in[3];
  const float* att_b   = (const float*)d_in[4];
  const float* cls_w   = (const float*)d_in[5];
  const float* cls_b   = (const float*)d_in[6];
  const float* reg_w   = (const float*)d_in[7];
  const float* reg_b   = (const float*)d_in[8];
  const float* anchors = (const float*)d_in[9];
  const int*   cut_x   = (const int*)d_in[10];
  const unsigned char* invalid = (const unsigned char*)d_in[11];
  float* out0 = (float*)d_out;
  float* out1 = out0 + (size_t)cM * 72;
  float* out2 = out1 + cM;
  float* out3 = out2 + cM;

  size_t off = 0;
  char* base = (char*)d_ws;
  auto carve = [&](size_t bytes) -> void* {
    void* r = base + off; off += (bytes + 255) & ~(size_t)255; return r;
  };
  float* fbuf            = (float*)carve((size_t)cNB * cAFC * cFH * cFW * 4);
  ushort_t* feat         = (ushort_t*)carve((size_t)cM * cD * 2);
  ushort_t* attw         = (ushort_t*)carve((size_t)cNPAD * cD * 2);
  ushort_t* Wt           = (ushort_t*)carve((size_t)80 * 1408 * 2);
  float* partial         = (float*)carve((size_t)44 * cM * 4);
  float* denom           = (float*)carve((size_t)cM * 4);

  size_t featT_full = (size_t)cNB * cFTR * cNPAD * 2, featT_one = (size_t)cFTR * cNPAD * 2;
  size_t af_full    = (size_t)cM * cD * 2,            af_one    = (size_t)cP * cD * 2;
  size_t pp_full    = (size_t)cM * cNPAD * 2,         pp_one    = (size_t)cNPAD * cNPAD * 2;

  size_t needA = off + featT_full + af_full + pp_full;
  size_t needB = off + featT_full + af_full + pp_one;
  int mode = (ws_size >= needA) ? 0 : ((ws_size >= needB) ? 1 : 2);

  ushort_t *featT, *af, *Pp;
  if (mode == 0)      { featT = (ushort_t*)carve(featT_full); af = (ushort_t*)carve(af_full); Pp = (ushort_t*)carve(pp_full); }
  else if (mode == 1) { featT = (ushort_t*)carve(featT_full); af = (ushort_t*)carve(af_full); Pp = (ushort_t*)carve(pp_one); }
  else                { featT = (ushort_t*)carve(featT_one);  af = (ushort_t*)carve(af_one);  Pp = (ushort_t*)carve(pp_one); }

  k_conv<<<440, 256, 0, stream>>>(x, conv_w, conv_b, fbuf);
  k_gather<<<(cM * cD + 255) / 256, 256, 0, stream>>>(fbuf, cut_x, invalid, feat);
  k_cvt_attw<<<(cNPAD * cD + 255) / 256, 256, 0, stream>>>(att_w, attw);
  k_build_wt<<<(80 * 1408 + 255) / 256, 256, 0, stream>>>(reg_w, cls_w, Wt);

  if (mode == 0) {
    k_transpose<<<dim3(44, 11, 8), 256, 0, stream>>>(feat, featT, 0);
    k_gemm_s2<<<174 * 22, 256, 0, stream>>>(feat, attw, att_b, Pp, partial, 0, cM, 0);
    k_denom<<<(cM + 255) / 256, 256, 0, stream>>>(partial, denom, Pp, cM, 0);
    k_gemm_pv2<<<8 * 22 * 6, 256, 0, stream>>>(Pp, featT, denom, af, 0, 0, 0, 0);
    k_gemm_out<<<174, 256, 0, stream>>>(af, feat, Wt, reg_b, cls_b, anchors,
                                        out0, out1, out2, out3, 0, cM, 0);
  } else if (mode == 1) {
    k_transpose<<<dim3(44, 11, 8), 256, 0, stream>>>(feat, featT, 0);
    for (int b = 0; b < cNB; ++b) {
      k_gemm_s2<<<22 * 22, 256, 0, stream>>>(feat, attw, att_b, Pp, partial, b * cP, cP, b * cP);
      k_denom<<<(cP + 255) / 256, 256, 0, stream>>>(partial, denom, Pp, cP, b * cP);
      k_gemm_pv2<<<22 * 6, 256, 0, stream>>>(Pp, featT, denom, af, b, b * cP, 0, 0);
    }
    k_gemm_out<<<174, 256, 0, stream>>>(af, feat, Wt, reg_b, cls_b, anchors,
                                        out0, out1, out2, out3, 0, cM, 0);
  } else {
    for (int b = 0; b < cNB; ++b) {
      k_transpose<<<dim3(44, 11, 1), 256, 0, stream>>>(feat, featT, b);
      k_gemm_s2<<<22 * 22, 256, 0, stream>>>(feat, attw, att_b, Pp, partial, b * cP, cP, b * cP);
      k_denom<<<(cP + 255) / 256, 256, 0, stream>>>(partial, denom, Pp, cP, b * cP);
      k_gemm_pv2<<<22 * 6, 256, 0, stream>>>(Pp, featT, denom, af, b, b * cP, b, b * cP);
      k_gemm_out<<<22, 256, 0, stream>>>(af, feat, Wt, reg_b, cls_b, anchors,
                                         out0, out1, out2, out3, b * cP, cP, b * cP);
    }
  }
}

// Round 5
// 458.050 us; speedup vs baseline: 1.9133x; 1.0074x over previous
//
#include <hip/hip_runtime.h>
#include <stdint.h>

typedef short short8 __attribute__((ext_vector_type(8)));
typedef float floatx4 __attribute__((ext_vector_type(4)));
typedef unsigned short ushort_t;

constexpr int cFH = 11, cFW = 20, cP = 2784, cPM1 = 2783, cD = 704;
constexpr int cAFC = 64, cBBC = 512, cNB = 8, cNPAD = 2816, cM = 22272;
constexpr int cFTR = 768;   // featT padded rows

static __device__ __forceinline__ unsigned short f2bf(float f) {
  union { float f; unsigned u; } v; v.f = f;
  unsigned r = v.u + 0x7fffu + ((v.u >> 16) & 1u);
  return (unsigned short)(r >> 16);
}
static __device__ __forceinline__ int imin(int a, int b) { return a < b ? a : b; }
// LDS XOR swizzle: position (row, pcol) holds global col pcol ^ swz8(row)
static __device__ __forceinline__ int swz8(int row) { return ((row >> 1) & 3) << 3; }

// bijective XCD-chunk swizzle (m204)
static __device__ __forceinline__ int xcd_swz(int orig, int total) {
  int q = total >> 3, r = total & 7;
  int xcd = orig & 7, pos = orig >> 3;
  return (xcd < r ? xcd * (q + 1) : r * (q + 1) + (xcd - r) * q) + pos;
}

// async global->LDS, 16B per lane, wave-uniform LDS base + lane*16
static __device__ __forceinline__ void gload16(const ushort_t* g, ushort_t* l) {
  __builtin_amdgcn_global_load_lds(
      (const __attribute__((address_space(1))) unsigned int*)g,
      (__attribute__((address_space(3))) unsigned int*)l, 16, 0, 0);
}

#define PIPE_BAR4() asm volatile("s_waitcnt vmcnt(4)\n\ts_barrier" ::: "memory")
#define PIPE_BAR0() asm volatile("s_waitcnt vmcnt(0)\n\ts_barrier" ::: "memory")

// ---------------- 1x1 conv, 4 output channels per thread
__global__ void k_conv4(const float* __restrict__ x, const float* __restrict__ w,
                        const float* __restrict__ bias, float* __restrict__ f) {
  int idx = blockIdx.x * 256 + threadIdx.x;
  if (idx >= cNB * 16 * 220) return;
  int yx = idx % 220;
  int og = (idx / 220) % 16;
  int b  = idx / (220 * 16);
  int o0 = og * 4;
  const float* xp = x + (size_t)b * cBBC * 220 + yx;
  const float* w0 = w + (size_t)o0 * cBBC;
  const float* w1 = w0 + cBBC;
  const float* w2 = w1 + cBBC;
  const float* w3 = w2 + cBBC;
  float a0 = 0.f, a1 = 0.f, a2 = 0.f, a3 = 0.f;
#pragma unroll 4
  for (int c = 0; c < cBBC; ++c) {
    float xv = xp[(size_t)c * 220];
    a0 += xv * w0[c]; a1 += xv * w1[c]; a2 += xv * w2[c]; a3 += xv * w3[c];
  }
  f[((size_t)(b * cAFC + o0) * 220) + yx]     = a0 + bias[o0];
  f[((size_t)(b * cAFC + o0 + 1) * 220) + yx] = a1 + bias[o0 + 1];
  f[((size_t)(b * cAFC + o0 + 2) * 220) + yx] = a2 + bias[o0 + 2];
  f[((size_t)(b * cAFC + o0 + 3) * 220) + yx] = a3 + bias[o0 + 3];
}

// ---------------- gather -> feat bf16 [22272][704], 8 elems/thread, short8 store
__global__ void k_gather8(const float* __restrict__ f, const int* __restrict__ cut_x,
                          const unsigned char* __restrict__ invalid,
                          ushort_t* __restrict__ feat) {
  int idx = blockIdx.x * 256 + threadIdx.x;
  if (idx >= cM * 88) return;
  int d8  = (idx % 88) * 8;
  int row = idx / 88;
  int p = row % cP;
  int b = row / cP;
  short8 v;
#pragma unroll
  for (int e = 0; e < 8; ++e) {
    int d = d8 + e;
    int o = d / cFH, i = d - o * cFH;
    int cx = cut_x[p * cFH + i];
    float vv = invalid[p * cFH + i] ? 0.f : f[((size_t)(b * cAFC + o) * cFH + i) * cFW + cx];
    v[e] = (short)f2bf(vv);
  }
  *(short8*)&feat[(size_t)row * cD + d8] = v;
}

// ---------------- feat -> featT bf16 [bz][768][2816]
__global__ void k_transpose(const ushort_t* __restrict__ feat,
                            ushort_t* __restrict__ featT, int b_base) {
  __shared__ ushort_t tile[64][66];
  int bz = blockIdx.z;
  int b  = b_base + bz;
  int p0 = blockIdx.x * 64, d0 = blockIdx.y * 64;
  int t = threadIdx.x;
#pragma unroll
  for (int m = 0; m < 16; ++m) {
    int idx = t + m * 256; int r = idx >> 6, c = idx & 63;
    int p = p0 + r;
    tile[r][c] = (p < cP) ? feat[((size_t)b * cP + p) * cD + d0 + c] : (ushort_t)0;
  }
  __syncthreads();
#pragma unroll
  for (int m = 0; m < 16; ++m) {
    int idx = t + m * 256; int r = idx >> 6, c = idx & 63;
    featT[((size_t)bz * cFTR + d0 + r) * cNPAD + p0 + c] = tile[c][r];
  }
}

// ---------------- att_w -> bf16 padded [2816][704]  +  Wt [80][1408], one launch
__global__ void k_prep_w(const float* __restrict__ att_w, const float* __restrict__ reg_w,
                         const float* __restrict__ cls_w,
                         ushort_t* __restrict__ attw, ushort_t* __restrict__ Wt) {
  int idx = blockIdx.x * 256 + threadIdx.x;
  constexpr int n1 = cNPAD * cD;
  if (idx < n1) {
    int r = idx / cD;
    attw[idx] = (r < cPM1) ? f2bf(att_w[idx]) : (ushort_t)0;
  } else {
    int j = idx - n1;
    if (j < 80 * 1408) {
      int r = j / 1408, k = j % 1408;
      float v = 0.f;
      if (r < 73) v = reg_w[(size_t)r * 1408 + k];
      else if (r < 75) v = cls_w[(size_t)(r - 73) * 1408 + k];
      Wt[j] = f2bf(v);
    }
  }
}

// ---------------- denom[i] = sum of 44 partial slots; zero Pp diagonal
__global__ void k_denom(const float* __restrict__ partial, float* __restrict__ denom,
                        ushort_t* __restrict__ Pp, int n, int p_base) {
  int i = blockIdx.x * 256 + threadIdx.x;
  if (i >= n) return;
  float s = 0.f;
#pragma unroll 4
  for (int q = 0; q < 44; ++q) s += partial[(size_t)q * cM + i];
  denom[i] = s;
  Pp[(size_t)i * cNPAD + ((p_base + i) % cP)] = 0;
}

// ---------------- GEMM 1 (3-buf pipelined): S = feat @ attw^T; exp; scatter; partials
__global__ __launch_bounds__(256, 4) void k_gemm_s2(
    const ushort_t* __restrict__ feat, const ushort_t* __restrict__ attw,
    const float* __restrict__ att_b, ushort_t* __restrict__ Pp,
    float* __restrict__ partial, int m_base, int m_count, int pp_base) {
  __shared__ __align__(16) ushort_t lds[3][8192];
  int wg = xcd_swz(blockIdx.x, gridDim.x);
  int ntile = wg % 22, mtile = wg / 22;
  int tid = threadIdx.x;
  int w = tid >> 6, l = tid & 63, lr = l & 15, lg = l >> 4;
  int wr = (w >> 1) * 64, wc = (w & 1) * 64;
  int m0 = m_base + mtile * 128;
  int n0 = ntile * 128;
  int rmaxA = m_base + m_count - 1;

  int srow = w * 16 + (l >> 2);
  int scol = ((l & 3) * 8) ^ swz8(srow);   // pre-swizzled global source col
  const ushort_t* a0 = feat + (size_t)imin(m0 + srow, rmaxA) * cD + scol;
  const ushort_t* a1 = feat + (size_t)imin(m0 + 64 + srow, rmaxA) * cD + scol;
  const ushort_t* b0 = attw + (size_t)(n0 + srow) * cD + scol;
  const ushort_t* b1 = attw + (size_t)(n0 + 64 + srow) * cD + scol;
  int w512 = w * 512;

  int offA[4], offB[4];
#pragma unroll
  for (int mt = 0; mt < 4; ++mt) {
    int row = wr + mt * 16 + lr;
    offA[mt] = row * 32 + ((lg * 8) ^ swz8(row));
  }
#pragma unroll
  for (int nt = 0; nt < 4; ++nt) {
    int row = wc + nt * 16 + lr;
    offB[nt] = 4096 + row * 32 + ((lg * 8) ^ swz8(row));
  }

  floatx4 acc[4][4];
  floatx4 zero = {0.f, 0.f, 0.f, 0.f};
#pragma unroll
  for (int a = 0; a < 4; ++a)
#pragma unroll
    for (int q = 0; q < 4; ++q) acc[a][q] = zero;

  auto stage = [&](int buf) {
    ushort_t* L = &lds[buf][w512];
    gload16(a0, L); gload16(a1, L + 2048);
    gload16(b0, L + 4096); gload16(b1, L + 6144);
    a0 += 32; a1 += 32; b0 += 32; b1 += 32;
  };

  stage(0); stage(1);
  int c0 = 0, c1 = 1, c2 = 2;
  constexpr int NK = cD / 32;  // 22
  for (int t = 0; t < NK; ++t) {
    if (t + 1 < NK) PIPE_BAR4(); else PIPE_BAR0();
    if (t + 2 < NK) stage(c2);
    const ushort_t* Lc = lds[c0];
    short8 av[4], bv[4];
#pragma unroll
    for (int mt = 0; mt < 4; ++mt) av[mt] = *(const short8*)(Lc + offA[mt]);
#pragma unroll
    for (int nt = 0; nt < 4; ++nt) bv[nt] = *(const short8*)(Lc + offB[nt]);
#pragma unroll
    for (int mt = 0; mt < 4; ++mt)
#pragma unroll
      for (int nt = 0; nt < 4; ++nt)
        acc[mt][nt] = __builtin_amdgcn_mfma_f32_16x16x32_bf16(av[mt], bv[nt], acc[mt][nt], 0, 0, 0);
    int tmp = c0; c0 = c1; c1 = c2; c2 = tmp;
  }

  // epilogue: exp, scatter store (diag skip), per-row partial sums
  int w1 = w & 1;
  float ab[4]; int kc[4];
#pragma unroll
  for (int nt = 0; nt < 4; ++nt) {
    int k = n0 + wc + nt * 16 + lr;
    kc[nt] = k;
    ab[nt] = (k < cPM1) ? att_b[k] : 0.f;
  }
#pragma unroll
  for (int mt = 0; mt < 4; ++mt) {
#pragma unroll
    for (int r = 0; r < 4; ++r) {
      int i = m0 + wr + mt * 16 + lg * 4 + r;
      int il = i - pp_base;
      bool rowok = (i - m_base) < m_count;
      int pl = i % cP;
      float s = 0.f;
#pragma unroll
      for (int nt = 0; nt < 4; ++nt) {
        int k = kc[nt];
        if (k < cPM1) {
          float e = __expf(acc[mt][nt][r] + ab[nt]);
          s += e;
          if (rowok) Pp[(size_t)il * cNPAD + k + (k >= pl ? 1 : 0)] = f2bf(e);
        } else if (k <= cNPAD - 2) {
          if (rowok) Pp[(size_t)il * cNPAD + k + 1] = 0;
        }
      }
      s += __shfl_xor(s, 1); s += __shfl_xor(s, 2);
      s += __shfl_xor(s, 4); s += __shfl_xor(s, 8);
      if (lr == 0 && rowok)
        partial[(size_t)(ntile * 2 + w1) * cM + il] = s;
    }
  }
}

// ---------------- GEMM 2 (3-buf pipelined): att_feat = (Pp @ featT^T) / denom
__global__ __launch_bounds__(256, 4) void k_gemm_pv2(
    const ushort_t* __restrict__ Pp, const ushort_t* __restrict__ featT,
    const float* __restrict__ denom, ushort_t* __restrict__ af,
    int b_base, int pp_base, int ft_base, int af_base) {
  __shared__ __align__(16) ushort_t lds[3][8192];
  int wg = xcd_swz(blockIdx.x, gridDim.x);
  int ntile = wg % 6;
  int t6 = wg / 6;
  int mtile = t6 % 22;
  int b = b_base + t6 / 22;
  int tid = threadIdx.x;
  int w = tid >> 6, l = tid & 63, lr = l & 15, lg = l >> 4;
  int wr = (w >> 1) * 64, wc = (w & 1) * 64;
  int m0l = mtile * 128;
  int n0 = ntile * 128;
  int bP = b * cP - pp_base;

  int srow = w * 16 + (l >> 2);
  int scol = ((l & 3) * 8) ^ swz8(srow);
  const ushort_t* a0 = Pp + (size_t)(bP + imin(m0l + srow, cP - 1)) * cNPAD + scol;
  const ushort_t* a1 = Pp + (size_t)(bP + imin(m0l + 64 + srow, cP - 1)) * cNPAD + scol;
  const ushort_t* b0 = featT + ((size_t)(b - ft_base) * cFTR + n0 + srow) * cNPAD + scol;
  const ushort_t* b1 = featT + ((size_t)(b - ft_base) * cFTR + n0 + 64 + srow) * cNPAD + scol;
  int w512 = w * 512;

  int offA[4], offB[4];
#pragma unroll
  for (int mt = 0; mt < 4; ++mt) {
    int row = wr + mt * 16 + lr;
    offA[mt] = row * 32 + ((lg * 8) ^ swz8(row));
  }
#pragma unroll
  for (int nt = 0; nt < 4; ++nt) {
    int row = wc + nt * 16 + lr;
    offB[nt] = 4096 + row * 32 + ((lg * 8) ^ swz8(row));
  }

  floatx4 acc[4][4];
  floatx4 zero = {0.f, 0.f, 0.f, 0.f};
#pragma unroll
  for (int a = 0; a < 4; ++a)
#pragma unroll
    for (int q = 0; q < 4; ++q) acc[a][q] = zero;

  auto stage = [&](int buf) {
    ushort_t* L = &lds[buf][w512];
    gload16(a0, L); gload16(a1, L + 2048);
    gload16(b0, L + 4096); gload16(b1, L + 6144);
    a0 += 32; a1 += 32; b0 += 32; b1 += 32;
  };

  stage(0); stage(1);
  int c0 = 0, c1 = 1, c2 = 2;
  constexpr int NK = cP / 32;  // 87 (pad cols contribute zero, skipped)
  for (int t = 0; t < NK; ++t) {
    if (t + 1 < NK) PIPE_BAR4(); else PIPE_BAR0();
    if (t + 2 < NK) stage(c2);
    const ushort_t* Lc = lds[c0];
    short8 av[4], bv[4];
#pragma unroll
    for (int mt = 0; mt < 4; ++mt) av[mt] = *(const short8*)(Lc + offA[mt]);
#pragma unroll
    for (int nt = 0; nt < 4; ++nt) bv[nt] = *(const short8*)(Lc + offB[nt]);
#pragma unroll
    for (int mt = 0; mt < 4; ++mt)
#pragma unroll
      for (int nt = 0; nt < 4; ++nt)
        acc[mt][nt] = __builtin_amdgcn_mfma_f32_16x16x32_bf16(av[mt], bv[nt], acc[mt][nt], 0, 0, 0);
    int tmp = c0; c0 = c1; c1 = c2; c2 = tmp;
  }

#pragma unroll
  for (int mt = 0; mt < 4; ++mt)
#pragma unroll
    for (int nt = 0; nt < 4; ++nt)
#pragma unroll
      for (int r = 0; r < 4; ++r) {
        int p = m0l + wr + mt * 16 + lg * 4 + r;
        int dd = n0 + wc + nt * 16 + lr;
        if (p < cP && dd < cD) {
          float v = acc[mt][nt][r] / denom[bP + p];
          af[((size_t)(b * cP + p) - af_base) * cD + dd] = f2bf(v);
        }
      }
}

// ---------------- GEMM 3 (staged A): [att_feat|feat] @ Wt^T + epilogue
__global__ __launch_bounds__(256, 4) void k_gemm_out(
    const ushort_t* __restrict__ af, const ushort_t* __restrict__ feat,
    const ushort_t* __restrict__ Wt,
    const float* __restrict__ reg_b, const float* __restrict__ cls_b,
    const float* __restrict__ anchors,
    float* __restrict__ out0, float* __restrict__ out1,
    float* __restrict__ out2, float* __restrict__ out3,
    int m_base, int m_count, int af_base) {
  __shared__ __align__(16) ushort_t sA[2][128 * 32];
  int tid = threadIdx.x;
  int w = tid >> 6, l = tid & 63, lr = l & 15, lg = l >> 4;
  int wr = w * 32;
  int m0 = m_base + blockIdx.x * 128;
  int lastRow = m_base + m_count - 1;

  int srow = w * 16 + (l >> 2), scol = (l & 3) * 8;
  const ushort_t* pa0_af = af + (size_t)(imin(m0 + srow, lastRow) - af_base) * cD + scol;
  const ushort_t* pa1_af = af + (size_t)(imin(m0 + 64 + srow, lastRow) - af_base) * cD + scol;
  const ushort_t* pa0_f  = feat + (size_t)imin(m0 + srow, lastRow) * cD + scol;
  const ushort_t* pa1_f  = feat + (size_t)imin(m0 + 64 + srow, lastRow) * cD + scol;
  int lbase = w * 512;

  floatx4 zero = {0.f, 0.f, 0.f, 0.f};
  floatx4 acc[2][5];
#pragma unroll
  for (int a = 0; a < 2; ++a)
#pragma unroll
    for (int q = 0; q < 5; ++q) acc[a][q] = zero;

  auto stageA = [&](int buf, int kk) {
    const ushort_t *s0, *s1;
    if (kk < 22) { s0 = pa0_af + kk * 32; s1 = pa1_af + kk * 32; }
    else         { s0 = pa0_f + (kk - 22) * 32; s1 = pa1_f + (kk - 22) * 32; }
    gload16(s0, &sA[buf][lbase]);
    gload16(s1, &sA[buf][lbase + 2048]);
  };

  stageA(0, 0);
  __syncthreads();
  int cur = 0;
  for (int kk = 0; kk < 44; ++kk) {
    if (kk + 1 < 44) stageA(cur ^ 1, kk + 1);
    int kb = kk * 32 + lg * 8;
    short8 avv[2];
#pragma unroll
    for (int mt = 0; mt < 2; ++mt)
      avv[mt] = *(const short8*)&sA[cur][(wr + mt * 16 + lr) * 32 + lg * 8];
#pragma unroll
    for (int nt = 0; nt < 5; ++nt) {
      short8 bvv = *(const short8*)(Wt + (size_t)(nt * 16 + lr) * 1408 + kb);
#pragma unroll
      for (int mt = 0; mt < 2; ++mt)
        acc[mt][nt] = __builtin_amdgcn_mfma_f32_16x16x32_bf16(avv[mt], bvv, acc[mt][nt], 0, 0, 0);
    }
    __syncthreads();
    cur ^= 1;
  }

#pragma unroll
  for (int mt = 0; mt < 2; ++mt)
#pragma unroll
    for (int nt = 0; nt < 5; ++nt)
#pragma unroll
      for (int r = 0; r < 4; ++r) {
        int i = m0 + wr + mt * 16 + lg * 4 + r;
        if (i - m_base >= m_count) continue;
        int o = nt * 16 + lr;
        int p = i % cP;
        float v = acc[mt][nt][r];
        const float* an = anchors + (size_t)p * 74;
        if (o == 0)        { out2[i] = an[1] + v + reg_b[0]; out1[i] = an[0]; }
        else if (o < 73)   { out0[(size_t)i * 72 + (o - 1)] = an[1 + o] + v + reg_b[o]; }
        else if (o == 73)  { out3[(size_t)i * 2]     = v + cls_b[0]; }
        else if (o == 74)  { out3[(size_t)i * 2 + 1] = v + cls_b[1]; }
      }
}

extern "C" void kernel_launch(void* const* d_in, const int* in_sizes, int n_in,
                              void* d_out, int out_size, void* d_ws, size_t ws_size,
                              hipStream_t stream) {
  const float* x       = (const float*)d_in[0];
  const float* conv_w  = (const float*)d_in[1];
  const float* conv_b  = (const float*)d_in[2];
  const float* att_w   = (const float*)d_in[3];
  const float* att_b   = (const float*)d_in[4];
  const float* cls_w   = (const float*)d_in[5];
  const float* cls_b   = (const float*)d_in[6];
  const float* reg_w   = (const float*)d_in[7];
  const float* reg_b   = (const float*)d_in[8];
  const float* anchors = (const float*)d_in[9];
  const int*   cut_x   = (const int*)d_in[10];
  const unsigned char* invalid = (const unsigned char*)d_in[11];
  float* out0 = (float*)d_out;
  float* out1 = out0 + (size_t)cM * 72;
  float* out2 = out1 + cM;
  float* out3 = out2 + cM;

  size_t off = 0;
  char* base = (char*)d_ws;
  auto carve = [&](size_t bytes) -> void* {
    void* r = base + off; off += (bytes + 255) & ~(size_t)255; return r;
  };
  float* fbuf            = (float*)carve((size_t)cNB * cAFC * cFH * cFW * 4);
  ushort_t* feat         = (ushort_t*)carve((size_t)cM * cD * 2);
  ushort_t* attw         = (ushort_t*)carve((size_t)cNPAD * cD * 2);
  ushort_t* Wt           = (ushort_t*)carve((size_t)80 * 1408 * 2);
  float* partial         = (float*)carve((size_t)44 * cM * 4);
  float* denom           = (float*)carve((size_t)cM * 4);

  size_t featT_full = (size_t)cNB * cFTR * cNPAD * 2, featT_one = (size_t)cFTR * cNPAD * 2;
  size_t af_full    = (size_t)cM * cD * 2,            af_one    = (size_t)cP * cD * 2;
  size_t pp_full    = (size_t)cM * cNPAD * 2,         pp_one    = (size_t)cNPAD * cNPAD * 2;

  size_t needA = off + featT_full + af_full + pp_full;
  size_t needB = off + featT_full + af_full + pp_one;
  int mode = (ws_size >= needA) ? 0 : ((ws_size >= needB) ? 1 : 2);

  ushort_t *featT, *af, *Pp;
  if (mode == 0)      { featT = (ushort_t*)carve(featT_full); af = (ushort_t*)carve(af_full); Pp = (ushort_t*)carve(pp_full); }
  else if (mode == 1) { featT = (ushort_t*)carve(featT_full); af = (ushort_t*)carve(af_full); Pp = (ushort_t*)carve(pp_one); }
  else                { featT = (ushort_t*)carve(featT_one);  af = (ushort_t*)carve(af_one);  Pp = (ushort_t*)carve(pp_one); }

  k_conv4<<<(cNB * 16 * 220 + 255) / 256, 256, 0, stream>>>(x, conv_w, conv_b, fbuf);
  k_gather8<<<(cM * 88 + 255) / 256, 256, 0, stream>>>(fbuf, cut_x, invalid, feat);
  k_prep_w<<<(cNPAD * cD + 80 * 1408 + 255) / 256, 256, 0, stream>>>(att_w, reg_w, cls_w, attw, Wt);

  if (mode == 0) {
    k_transpose<<<dim3(44, 11, 8), 256, 0, stream>>>(feat, featT, 0);
    k_gemm_s2<<<174 * 22, 256, 0, stream>>>(feat, attw, att_b, Pp, partial, 0, cM, 0);
    k_denom<<<(cM + 255) / 256, 256, 0, stream>>>(partial, denom, Pp, cM, 0);
    k_gemm_pv2<<<8 * 22 * 6, 256, 0, stream>>>(Pp, featT, denom, af, 0, 0, 0, 0);
    k_gemm_out<<<174, 256, 0, stream>>>(af, feat, Wt, reg_b, cls_b, anchors,
                                        out0, out1, out2, out3, 0, cM, 0);
  } else if (mode == 1) {
    k_transpose<<<dim3(44, 11, 8), 256, 0, stream>>>(feat, featT, 0);
    for (int b = 0; b < cNB; ++b) {
      k_gemm_s2<<<22 * 22, 256, 0, stream>>>(feat, attw, att_b, Pp, partial, b * cP, cP, b * cP);
      k_denom<<<(cP + 255) / 256, 256, 0, stream>>>(partial, denom, Pp, cP, b * cP);
      k_gemm_pv2<<<22 * 6, 256, 0, stream>>>(Pp, featT, denom, af, b, b * cP, 0, 0);
    }
    k_gemm_out<<<174, 256, 0, stream>>>(af, feat, Wt, reg_b, cls_b, anchors,
                                        out0, out1, out2, out3, 0, cM, 0);
  } else {
    for (int b = 0; b < cNB; ++b) {
      k_transpose<<<dim3(44, 11, 1), 256, 0, stream>>>(feat, featT, b);
      k_gemm_s2<<<22 * 22, 256, 0, stream>>>(feat, attw, att_b, Pp, partial, b * cP, cP, b * cP);
      k_denom<<<(cP + 255) / 256, 256, 0, stream>>>(partial, denom, Pp, cP, b * cP);
      k_gemm_pv2<<<22 * 6, 256, 0, stream>>>(Pp, featT, denom, af, b, b * cP, b, b * cP);
      k_gemm_out<<<22, 256, 0, stream>>>(af, feat, Wt, reg_b, cls_b, anchors,
                                         out0, out1, out2, out3, b * cP, cP, b * cP);
    }
  }
}